// Round 8
// baseline (180.577 us; speedup 1.0000x reference)
//
#include <hip/hip_runtime.h>
#include <math.h>

#define Bsz 8192
#define Dd  128
#define BM  64                     // rows per main block
#define NSLICE 8                   // j-slices, keyed to XCD = blockIdx & 7
#define NTILE  (512 / NSLICE / 4)  // col-tiles PER WAVE = 512 / slices / 4 waves = 16

typedef __attribute__((ext_vector_type(8))) short short8;   // 8 bf16 = 4 VGPR
typedef __attribute__((ext_vector_type(4))) float float4v;  // MFMA C/D frag

static constexpr float INV_T = 1.0f / 0.07f;  // logit scale; also fixed logsumexp shift
static constexpr float K1 =  20.60992915555662f;   // (1/T)*log2(e)
static constexpr float K2 = -20.60992915555662f;   // exp((S-1)/T) == exp2(S*K1 + K2)
// fixed-point fused finish: u64 = (count << 55) | sum*2^40
// Each row receives NSLICE*4 = 32 contributions (4 waves per slice-block, each
// covering ALL 64 rows -- waves partition COLUMNS).  Bounds: per-wave rowsum
// <= 256 cols * 1.0 (terms <= e^{(Smax-1)/T} = 1) -> *2^40 = 2^48; 32 adds
// < 2^53 < 2^55.  Count (<=32) in bits 55..63.  Truncation 32*2^-40: negligible.
static constexpr float SCALE     = 1099511627776.0f;   // 2^40 (exact in f32)
static constexpr float INV_SCALE = 1.0f / 1099511627776.0f;
#define CNT_SHIFT 55
#define NCONTRIB  (NSLICE * 4)     // 32 contributions per row
#define SUM_MASK  ((1ULL << CNT_SHIFT) - 1ULL)

// RNE float->bf16 pack (x -> low16, y -> high16)
static __device__ inline unsigned pack_bf16(float x, float y) {
    union { float f; unsigned u; } a, b;
    a.f = x; b.f = y;
    unsigned ra = a.u + 0x7FFF + ((a.u >> 16) & 1);
    unsigned rb = b.u + 0x7FFF + ((b.u >> 16) & 1);
    return (ra >> 16) | (rb & 0xFFFF0000u);
}

// ---------------- init: zero the packed compaction counter ----------------
__global__ void init_kernel(unsigned long long* __restrict__ cnt) {
    if (threadIdx.x == 0) cnt[0] = 0ull;
}

// ---------------- prep: 32 rows/block, float4 loads, half-wave butterflies ----
// 1024 threads = 16 waves; wave w owns rows (2w, 2w+1): lane<32 -> row 2w, else 2w+1.
// Lane's c = lane&31 indexes the row's float4 chunk. ONE packed atomic per block.
__global__ __launch_bounds__(1024) void prep_kernel(
    const float4* __restrict__ fv4, const float4* __restrict__ fi4,
    const float4* __restrict__ v4,  const float4* __restrict__ vi4,
    unsigned* __restrict__ Xb, uint2* __restrict__ Yf0, uint2* __restrict__ Yf1,
    float* __restrict__ posArr, int* __restrict__ origArr, int* __restrict__ flagArr,
    unsigned long long* __restrict__ lAcc64, unsigned long long* __restrict__ cnt)
{
    __shared__ unsigned sT0[32 * 66];   // row stride 66 words (even: uint2-aligned)
    __shared__ unsigned sT1[32 * 66];
    __shared__ int sFlagL[32];
    __shared__ int sRank[32];
    __shared__ unsigned sBase[2];

    const int t    = threadIdx.x;
    const int wave = t >> 6;
    const int lane = t & 63;
    const int half = lane >> 5;
    const int c    = lane & 31;
    const int rl   = wave * 2 + half;          // row-local 0..31
    const int b    = blockIdx.x * 32 + rl;     // global row
    const int src  = b * 32 + c;               // float4 index into [B,128]

    const float4 afv = fv4[src];
    const float4 afi = fi4[src];
    const float4 av  = v4[src];
    const float4 avi = vi4[src];

    float nfv = afv.x*afv.x + afv.y*afv.y + afv.z*afv.z + afv.w*afv.w;
    float nfi = afi.x*afi.x + afi.y*afi.y + afi.z*afi.z + afi.w*afi.w;
    float nv  = av.x*av.x   + av.y*av.y   + av.z*av.z   + av.w*av.w;
    float nvi = avi.x*avi.x + avi.y*avi.y + avi.z*avi.z + avi.w*avi.w;
    float dv  = afv.x*av.x  + afv.y*av.y  + afv.z*av.z  + afv.w*av.w;
    float di  = afi.x*avi.x + afi.y*avi.y + afi.z*avi.z + afi.w*avi.w;

    #pragma unroll
    for (int m = 1; m < 32; m <<= 1) {   // half-wave butterfly (rows are 32-lane groups)
        nfv += __shfl_xor(nfv, m);
        nfi += __shfl_xor(nfi, m);
        nv  += __shfl_xor(nv,  m);
        nvi += __shfl_xor(nvi, m);
        dv  += __shfl_xor(dv,  m);
        di  += __shfl_xor(di,  m);
    }

    const float rnfv = 1.0f / fmaxf(sqrtf(nfv), 1e-12f);
    const float rnfi = 1.0f / fmaxf(sqrtf(nfi), 1e-12f);
    const float rnv  = 1.0f / fmaxf(sqrtf(nv ), 1e-12f);
    const float rnvi = 1.0f / fmaxf(sqrtf(nvi), 1e-12f);

    const float pos_v = dv * rnfv * rnv;
    const float pos_i = di * rnfi * rnvi;
    const bool useV = (pos_v >= pos_i);
    const float pos = useV ? pos_v : pos_i;

    // stage normalized Y rows as packed d-pair words for the fragment transpose
    uint2 w0y = make_uint2(pack_bf16(av.x  * rnv,  av.y  * rnv),
                           pack_bf16(av.z  * rnv,  av.w  * rnv));
    uint2 w1y = make_uint2(pack_bf16(avi.x * rnvi, avi.y * rnvi),
                           pack_bf16(avi.z * rnvi, avi.w * rnvi));
    *(uint2*)&sT0[rl * 66 + c * 2] = w0y;
    *(uint2*)&sT1[rl * 66 + c * 2] = w1y;
    if (c == 0) sFlagL[rl] = useV ? 0 : 1;
    __syncthreads();

    // wave 0: block-local ranks + ONE packed 64-bit atomic for both counters
    if (t < 64) {
        const int f = (lane < 32) ? sFlagL[lane] : 2;
        const unsigned long long m0 = __ballot(f == 0);
        const unsigned long long m1 = __ballot(f == 1);
        if (lane == 0) {
            const unsigned long long add =
                (unsigned long long)__popcll(m0) | ((unsigned long long)__popcll(m1) << 32);
            const unsigned long long ret = atomicAdd(cnt, add);
            sBase[0] = (unsigned)(ret & 0xffffffffull);
            sBase[1] = (unsigned)(ret >> 32);
        }
        if (lane < 32) {
            const unsigned long long below = (1ull << lane) - 1ull;
            sRank[lane] = (f == 0) ? (int)__popcll(m0 & below) : (int)__popcll(m1 & below);
        }
    }

    // fragment-ordered Yf write (independent of compaction; overlaps the atomic)
    // uint2 u = blk*1024 + t  <->  words o=2t: tl=t>>9, kc=(t>>7)&3, lp=(t>>1)&63, w0=(t&1)*2
    {
        const int tl = t >> 9;
        const int kc = (t >> 7) & 3;
        const int lp = (t >> 1) & 63;
        const int w0 = (t & 1) * 2;
        const int row = tl * 16 + (lp & 15);
        const int s   = kc * 16 + (lp >> 4) * 4 + w0;   // d-pair word within row
        Yf0[blockIdx.x * 1024 + t] = *(const uint2*)&sT0[row * 66 + s];
        Yf1[blockIdx.x * 1024 + t] = *(const uint2*)&sT1[row * 66 + s];
    }
    __syncthreads();

    const int f  = sFlagL[rl];
    const int rk = sRank[rl];
    const int p  = (f == 0) ? (int)(sBase[0] + rk) : (Bsz - 1 - (int)(sBase[1] + rk));

    // single predicated X store (select flavor in registers, one 8B store)
    const float sc = useV ? rnfv : rnfi;
    const float x0 = useV ? afv.x : afi.x;
    const float x1 = useV ? afv.y : afi.y;
    const float x2 = useV ? afv.z : afi.z;
    const float x3 = useV ? afv.w : afi.w;
    ((uint2*)Xb)[p * 32 + c] = make_uint2(pack_bf16(x0 * sc, x1 * sc),
                                          pack_bf16(x2 * sc, x3 * sc));

    if (c == 0) {
        posArr[p]  = pos;
        origArr[p] = b;
        flagArr[p] = f;
        lAcc64[p]  = 0ull;          // zero (count | sum) accumulator
    }
}

// ---------------- main: BM=64, XCD-sliced, no-LDS prologue, exp/MFMA pipeline ----
// grid 1024 1-D: slice = blk&7 (XCD-keyed j-range), rowblk = blk>>3.
// 4 waves: each owns ALL 64 rows (afr[4][4]) and NTILE=16 of the slice's
// 64 col-tiles.  A/B frag: [m|n=lane&15][k=quad*8+j]; C/D: col=lane&15,
// row=quad*4+reg.
//
// Round-8 changes (from round-7 counters: bank-conflicts scale with block
// count => staging is the fixed cost; occupancy up + dur up => loop is
// dependency-serialized, not TLP-starved):
//  * NO LDS X-staging: afr[rt][kc] is a plain 16B row-segment of Xb --
//    load it directly from global (16 x 16B per lane, once per block).
//    Removes the stage loop, one barrier, 16 ds_read_b128, all bank
//    conflicts.  LDS = 264 B.
//  * exp/MFMA software pipeline (two named acc sets): while tile t+1's
//    MFMAs fill accB, tile t's exp/fma/add issue from accA on the
//    VALU+trans pipes -- independent data, separate pipes, true overlap.
//    Mid-step b0..b3 reload (round-0 proven) prefetches tile t+2's frags.
//  * NSLICE=8, 1024 blocks, (256,4) -- halve the per-block fixed cost.
//  * fused finish, ZERO fences (round-1 lesson): 32 contributions/row via
//    ONE relaxed u64 atomicAdd of (1<<55 | sum*2^40); 32nd adder writes
//    the loss.  No finish kernel.
__global__ __launch_bounds__(256, 4) void main_kernel(
    const unsigned short* __restrict__ Xb,
    const uint4* __restrict__ Yf0q, const uint4* __restrict__ Yf1q,
    const int* __restrict__ flagArr, unsigned long long* __restrict__ lAcc64,
    const float* __restrict__ posArr, const int* __restrict__ origArr,
    float* __restrict__ out)
{
    __shared__ int sFlag[BM];
    __shared__ int sHas[2];

    const int t    = threadIdx.x;
    const int wave = t >> 6;
    const int lane = t & 63;
    const int quad = lane >> 4;
    const int mrow = lane & 15;
    const int slice = blockIdx.x & (NSLICE - 1);
    const int p0    = (blockIdx.x >> 3) * BM;

    // direct-global A fragments: afr[rt][kc] = X[p0+rt*16+mrow][kc*32+quad*8 ..+7]
    short8 afr[4][4];
    #pragma unroll
    for (int rt = 0; rt < 4; ++rt)
        #pragma unroll
        for (int kc = 0; kc < 4; ++kc)
            afr[rt][kc] = *(const short8*)&Xb[(size_t)(p0 + rt * 16 + mrow) * 128
                                              + kc * 32 + quad * 8];

    // wave 0: flags + has-flavor bits via ballot; ONE barrier total
    if (t < 64) {
        const int f = flagArr[p0 + t];
        sFlag[t] = f;
        const unsigned long long m0 = __ballot(f == 0);
        const unsigned long long m1 = __ballot(f == 1);
        if (t == 0) { sHas[0] = (m0 != 0ull); sHas[1] = (m1 != 0ull); }
    }
    __syncthreads();

    const int g0 = slice * (NTILE * 4) + wave * NTILE;  // first col-tile for this wave

#define MFMA4(ACC, KC, BB)                                                         \
    _Pragma("unroll")                                                              \
    for (int rt = 0; rt < 4; ++rt)                                                 \
        ACC[rt] = __builtin_amdgcn_mfma_f32_16x16x32_bf16(afr[rt][KC], BB, ACC[rt], 0, 0, 0);

#define EXPQ(P, RT)                                                                \
    _Pragma("unroll")                                                              \
    for (int r = 0; r < 4; ++r)                                                    \
        rowsum[RT][r] += exp2f(fmaf(P[RT][r], K1, K2));

    // one pipeline step: MFMA this tile into ACC; exp previous tile's PACC;
    // mid-step reload b0..b3 with the NEXT tile's fragments (if PF)
#define STEP(ACC, PACC, PF) do {                                                   \
        ACC[0] = (float4v){0.f,0.f,0.f,0.f}; ACC[1] = (float4v){0.f,0.f,0.f,0.f};  \
        ACC[2] = (float4v){0.f,0.f,0.f,0.f}; ACC[3] = (float4v){0.f,0.f,0.f,0.f};  \
        MFMA4(ACC, 0, b0); MFMA4(ACC, 1, b1);                                      \
        EXPQ(PACC, 0); EXPQ(PACC, 1);                                              \
        if (PF) { b0 = *(const short8*)&yb[256]; b1 = *(const short8*)&yb[320]; }  \
        MFMA4(ACC, 2, b2); MFMA4(ACC, 3, b3);                                      \
        EXPQ(PACC, 2); EXPQ(PACC, 3);                                              \
        if (PF) { b2 = *(const short8*)&yb[384]; b3 = *(const short8*)&yb[448]; }  \
        yb += 256;                                                                 \
    } while (0)

#define STEP0(ACC, PF) do {                                                        \
        ACC[0] = (float4v){0.f,0.f,0.f,0.f}; ACC[1] = (float4v){0.f,0.f,0.f,0.f};  \
        ACC[2] = (float4v){0.f,0.f,0.f,0.f}; ACC[3] = (float4v){0.f,0.f,0.f,0.f};  \
        MFMA4(ACC, 0, b0); MFMA4(ACC, 1, b1);                                      \
        if (PF) { b0 = *(const short8*)&yb[256]; b1 = *(const short8*)&yb[320]; }  \
        MFMA4(ACC, 2, b2); MFMA4(ACC, 3, b3);                                      \
        if (PF) { b2 = *(const short8*)&yb[384]; b3 = *(const short8*)&yb[448]; }  \
        yb += 256;                                                                 \
    } while (0)

    for (int phase = 0; phase < 2; ++phase) {
        if (!sHas[phase]) continue;          // flavor-pure blocks run one phase
        const uint4* __restrict__ yb = (phase ? Yf1q : Yf0q) + (size_t)g0 * 256 + lane;

        float rowsum[4][4] = {};             // unconditional per-phase exp-sums
        float4v accA[4], accB[4];

        short8 b0 = *(const short8*)&yb[0];      // tile g0, kc0
        short8 b1 = *(const short8*)&yb[64];     // kc1
        short8 b2 = *(const short8*)&yb[128];    // kc2
        short8 b3 = *(const short8*)&yb[192];    // kc3

        STEP0(accA, 1);                      // tile 0 (prefetches tile 1)
        #pragma unroll 1
        for (int i = 0; i < 7; ++i) {
            STEP(accB, accA, 1);             // tiles 1,3,..,13 ; exp of prev
            STEP(accA, accB, 1);             // tiles 2,4,..,14 ; exp of prev
        }
        STEP(accB, accA, 0);                 // tile 15 ; exp of tile 14
        EXPQ(accB, 0); EXPQ(accB, 1); EXPQ(accB, 2); EXPQ(accB, 3);  // tile 15

        // reduce over the 16 col-lanes of each quad
        #pragma unroll
        for (int m = 1; m < 16; m <<= 1)
            #pragma unroll
            for (int rt = 0; rt < 4; ++rt)
                #pragma unroll
                for (int r = 0; r < 4; ++r)
                    rowsum[rt][r] += __shfl_xor(rowsum[rt][r], m);

        // flag-predicated packed atomic; 32nd contributor writes the loss
        if (mrow == 0) {
            #pragma unroll
            for (int rt = 0; rt < 4; ++rt)
                #pragma unroll
                for (int r = 0; r < 4; ++r) {
                    const int row = rt * 16 + quad * 4 + r;
                    if (sFlag[row] == phase) {
                        const unsigned long long add =
                            (unsigned long long)(rowsum[rt][r] * SCALE)
                            | (1ULL << CNT_SHIFT);
                        const unsigned long long ret =
                            atomicAdd(&lAcc64[p0 + row], add);
                        if ((ret >> CNT_SHIFT) == NCONTRIB - 1) {
                            const unsigned long long tot = (ret + add) & SUM_MASK;
                            const float s = (float)tot * INV_SCALE;
                            out[origArr[p0 + row]] =
                                logf(s) + INV_T - posArr[p0 + row] * INV_T;
                        }
                    }
                }
        }
    }
#undef STEP0
#undef STEP
#undef EXPQ
#undef MFMA4
}

// ---------------- launch ----------------
extern "C" void kernel_launch(void* const* d_in, const int* in_sizes, int n_in,
                              void* d_out, int out_size, void* d_ws, size_t ws_size,
                              hipStream_t stream)
{
    const float4* fv = (const float4*)d_in[0];
    const float4* fi = (const float4*)d_in[1];
    const float4* v  = (const float4*)d_in[2];
    const float4* vi = (const float4*)d_in[3];
    float* out = (float*)d_out;

    unsigned short* Xb  = (unsigned short*)d_ws;   // [B,128] bf16 row-major, compacted X
    unsigned short* Yf0 = Xb  + Bsz * Dd;          // [B*128] bf16, B-fragment-ordered v
    unsigned short* Yf1 = Yf0 + Bsz * Dd;          // [B*128] bf16, B-fragment-ordered vi
    float* posArr = (float*)(Yf1 + Bsz * Dd);      // [B] positive logit (compacted idx)
    unsigned long long* lAcc64 =
        (unsigned long long*)(posArr + Bsz);       // [B] (count<<55 | sum*2^40)
    int*  origArr = (int*)(lAcc64 + Bsz);          // [B] compacted -> original row
    int*  flagArr = origArr + Bsz;                 // [B] flavor per compacted row
    unsigned long long* cnt = (unsigned long long*)(flagArr + Bsz);

    hipLaunchKernelGGL(init_kernel, dim3(1), dim3(64), 0, stream, cnt);
    hipLaunchKernelGGL(prep_kernel, dim3(Bsz / 32), dim3(1024), 0, stream,
                       fv, fi, v, vi, (unsigned*)Xb, (uint2*)Yf0, (uint2*)Yf1,
                       posArr, origArr, flagArr, lAcc64, cnt);
    hipLaunchKernelGGL(main_kernel, dim3((Bsz / BM) * NSLICE), dim3(256), 0, stream,
                       Xb, (const uint4*)Yf0, (const uint4*)Yf1, flagArr, lAcc64,
                       posArr, origArr, out);
}

// Round 9
// 119.732 us; speedup vs baseline: 1.5082x; 1.5082x over previous
//
#include <hip/hip_runtime.h>
#include <math.h>

#define Bsz 8192
#define Dd  128
#define BM  64                     // rows per main block
#define NSLICE 8                   // j-slices, keyed to XCD = blockIdx & 7
#define NTILE  (512 / NSLICE / 2)  // col-tiles PER WAVE = 512 / slices / 2 col-waves = 32

typedef __attribute__((ext_vector_type(8))) short short8;   // 8 bf16 = 4 VGPR
typedef __attribute__((ext_vector_type(4))) float float4v;  // MFMA C/D frag

static constexpr float INV_T = 1.0f / 0.07f;  // logit scale; also fixed logsumexp shift
static constexpr float K1 =  20.60992915555662f;   // (1/T)*log2(e)
static constexpr float K2 = -20.60992915555662f;   // exp((S-1)/T) == exp2(S*K1 + K2)
// fixed-point fused finish: u64 = (count << 55) | sum*2^40
// Each row receives NSLICE*2 = 16 contributions (2 col-waves per slice-block
// cover each row; the 2 row-waves own disjoint rows).  Bounds: per-wave
// rowsum <= 512 cols * 1.0 (terms <= e^{(Smax-1)/T} = 1) -> *2^40 = 2^49;
// 16 adds < 2^53 < 2^55.  Count (<=16) in bits 55..63.  Trunc 16*2^-40: negligible.
static constexpr float SCALE     = 1099511627776.0f;   // 2^40 (exact in f32)
static constexpr float INV_SCALE = 1.0f / 1099511627776.0f;
#define CNT_SHIFT 55
#define NCONTRIB  (NSLICE * 2)     // 16 contributions per row
#define SUM_MASK  ((1ULL << CNT_SHIFT) - 1ULL)

// RNE float->bf16 pack (x -> low16, y -> high16)
static __device__ inline unsigned pack_bf16(float x, float y) {
    union { float f; unsigned u; } a, b;
    a.f = x; b.f = y;
    unsigned ra = a.u + 0x7FFF + ((a.u >> 16) & 1);
    unsigned rb = b.u + 0x7FFF + ((b.u >> 16) & 1);
    return (ra >> 16) | (rb & 0xFFFF0000u);
}

// ---------------- init: zero the packed compaction counter ----------------
__global__ void init_kernel(unsigned long long* __restrict__ cnt) {
    if (threadIdx.x == 0) cnt[0] = 0ull;
}

// ---------------- prep: 32 rows/block, float4 loads, half-wave butterflies ----
// 1024 threads = 16 waves; wave w owns rows (2w, 2w+1): lane<32 -> row 2w, else 2w+1.
// Lane's c = lane&31 indexes the row's float4 chunk. ONE packed atomic per block.
__global__ __launch_bounds__(1024) void prep_kernel(
    const float4* __restrict__ fv4, const float4* __restrict__ fi4,
    const float4* __restrict__ v4,  const float4* __restrict__ vi4,
    unsigned* __restrict__ Xb, uint2* __restrict__ Yf0, uint2* __restrict__ Yf1,
    float* __restrict__ posArr, int* __restrict__ origArr, int* __restrict__ flagArr,
    unsigned long long* __restrict__ lAcc64, unsigned long long* __restrict__ cnt)
{
    __shared__ unsigned sT0[32 * 66];   // row stride 66 words (even: uint2-aligned)
    __shared__ unsigned sT1[32 * 66];
    __shared__ int sFlagL[32];
    __shared__ int sRank[32];
    __shared__ unsigned sBase[2];

    const int t    = threadIdx.x;
    const int wave = t >> 6;
    const int lane = t & 63;
    const int half = lane >> 5;
    const int c    = lane & 31;
    const int rl   = wave * 2 + half;          // row-local 0..31
    const int b    = blockIdx.x * 32 + rl;     // global row
    const int src  = b * 32 + c;               // float4 index into [B,128]

    const float4 afv = fv4[src];
    const float4 afi = fi4[src];
    const float4 av  = v4[src];
    const float4 avi = vi4[src];

    float nfv = afv.x*afv.x + afv.y*afv.y + afv.z*afv.z + afv.w*afv.w;
    float nfi = afi.x*afi.x + afi.y*afi.y + afi.z*afi.z + afi.w*afi.w;
    float nv  = av.x*av.x   + av.y*av.y   + av.z*av.z   + av.w*av.w;
    float nvi = avi.x*avi.x + avi.y*avi.y + avi.z*avi.z + avi.w*avi.w;
    float dv  = afv.x*av.x  + afv.y*av.y  + afv.z*av.z  + afv.w*av.w;
    float di  = afi.x*avi.x + afi.y*avi.y + afi.z*avi.z + afi.w*avi.w;

    #pragma unroll
    for (int m = 1; m < 32; m <<= 1) {   // half-wave butterfly (rows are 32-lane groups)
        nfv += __shfl_xor(nfv, m);
        nfi += __shfl_xor(nfi, m);
        nv  += __shfl_xor(nv,  m);
        nvi += __shfl_xor(nvi, m);
        dv  += __shfl_xor(dv,  m);
        di  += __shfl_xor(di,  m);
    }

    const float rnfv = 1.0f / fmaxf(sqrtf(nfv), 1e-12f);
    const float rnfi = 1.0f / fmaxf(sqrtf(nfi), 1e-12f);
    const float rnv  = 1.0f / fmaxf(sqrtf(nv ), 1e-12f);
    const float rnvi = 1.0f / fmaxf(sqrtf(nvi), 1e-12f);

    const float pos_v = dv * rnfv * rnv;
    const float pos_i = di * rnfi * rnvi;
    const bool useV = (pos_v >= pos_i);
    const float pos = useV ? pos_v : pos_i;

    // stage normalized Y rows as packed d-pair words for the fragment transpose
    uint2 w0y = make_uint2(pack_bf16(av.x  * rnv,  av.y  * rnv),
                           pack_bf16(av.z  * rnv,  av.w  * rnv));
    uint2 w1y = make_uint2(pack_bf16(avi.x * rnvi, avi.y * rnvi),
                           pack_bf16(avi.z * rnvi, avi.w * rnvi));
    *(uint2*)&sT0[rl * 66 + c * 2] = w0y;
    *(uint2*)&sT1[rl * 66 + c * 2] = w1y;
    if (c == 0) sFlagL[rl] = useV ? 0 : 1;
    __syncthreads();

    // wave 0: block-local ranks + ONE packed 64-bit atomic for both counters
    if (t < 64) {
        const int f = (lane < 32) ? sFlagL[lane] : 2;
        const unsigned long long m0 = __ballot(f == 0);
        const unsigned long long m1 = __ballot(f == 1);
        if (lane == 0) {
            const unsigned long long add =
                (unsigned long long)__popcll(m0) | ((unsigned long long)__popcll(m1) << 32);
            const unsigned long long ret = atomicAdd(cnt, add);
            sBase[0] = (unsigned)(ret & 0xffffffffull);
            sBase[1] = (unsigned)(ret >> 32);
        }
        if (lane < 32) {
            const unsigned long long below = (1ull << lane) - 1ull;
            sRank[lane] = (f == 0) ? (int)__popcll(m0 & below) : (int)__popcll(m1 & below);
        }
    }

    // fragment-ordered Yf write (independent of compaction; overlaps the atomic)
    // uint2 u = blk*1024 + t  <->  words o=2t: tl=t>>9, kc=(t>>7)&3, lp=(t>>1)&63, w0=(t&1)*2
    {
        const int tl = t >> 9;
        const int kc = (t >> 7) & 3;
        const int lp = (t >> 1) & 63;
        const int w0 = (t & 1) * 2;
        const int row = tl * 16 + (lp & 15);
        const int s   = kc * 16 + (lp >> 4) * 4 + w0;   // d-pair word within row
        Yf0[blockIdx.x * 1024 + t] = *(const uint2*)&sT0[row * 66 + s];
        Yf1[blockIdx.x * 1024 + t] = *(const uint2*)&sT1[row * 66 + s];
    }
    __syncthreads();

    const int f  = sFlagL[rl];
    const int rk = sRank[rl];
    const int p  = (f == 0) ? (int)(sBase[0] + rk) : (Bsz - 1 - (int)(sBase[1] + rk));

    // single predicated X store (select flavor in registers, one 8B store)
    const float sc = useV ? rnfv : rnfi;
    const float x0 = useV ? afv.x : afi.x;
    const float x1 = useV ? afv.y : afi.y;
    const float x2 = useV ? afv.z : afi.z;
    const float x3 = useV ? afv.w : afi.w;
    ((uint2*)Xb)[p * 32 + c] = make_uint2(pack_bf16(x0 * sc, x1 * sc),
                                          pack_bf16(x2 * sc, x3 * sc));

    if (c == 0) {
        posArr[p]  = pos;
        origArr[p] = b;
        flagArr[p] = f;
        lAcc64[p]  = 0ull;          // zero (count | sum) accumulator
    }
}

// ---------------- main: BM=64, 2x2 wave split, direct-global A, fused finish ----
// grid 1024 1-D: slice = blk&7 (XCD-keyed j-range), rowblk = blk>>3.
// 4 waves = 2 row-halves x 2 col-halves: wave w owns rows [wr*32, wr*32+32)
// via afr[2][4] (32 VGPR) and NTILE=32 col-tiles [slice*64 + wc*32 ...).
// A/B frag: [m|n=lane&15][k=quad*8+j]; C/D: col=lane&15, row=quad*4+reg.
//
// Round-9 rationale (from round-8 counters: VGPR=64 + 122/118 MB FETCH/WRITE
// = scratch spill; rounds 5/7/8 show the allocator gives this kernel 64-80
// VGPRs no matter the cap):
//  * Size the persistent state to the allocator's revealed budget: afr[2][4]
//    = 32 VGPR; total live ~80.  No spill, no LDS re-read.
//  * Direct-global afr (8 x 16B, once per block; X is L2-resident): no LDS
//    staging, no stage barrier, zero bank conflicts.  LDS = 264 B.
//  * The two wr-waves stream the SAME tile sequence -> 2nd wave's B-frag
//    loads hit L1; Y L2-traffic stays ~268 MB total.
//  * Loop body = round-2's proven mid-tile split prefetch (reload b0/b1
//    after kc1, b2/b3 after kc3), 32 tiles.
//  * fused finish, ZERO fences (round-1 lesson): 16 contributions/row via
//    ONE relaxed u64 atomicAdd of (1<<55 | sum*2^40); 16th adder writes
//    the loss.  No finish kernel.
__global__ __launch_bounds__(256, 4) void main_kernel(
    const unsigned short* __restrict__ Xb,
    const uint4* __restrict__ Yf0q, const uint4* __restrict__ Yf1q,
    const int* __restrict__ flagArr, unsigned long long* __restrict__ lAcc64,
    const float* __restrict__ posArr, const int* __restrict__ origArr,
    float* __restrict__ out)
{
    __shared__ int sFlag[BM];
    __shared__ int sHas[2];

    const int t    = threadIdx.x;
    const int wave = t >> 6;
    const int wr   = wave >> 1;        // row half 0/1
    const int wc   = wave & 1;         // col half 0/1
    const int lane = t & 63;
    const int quad = lane >> 4;
    const int mrow = lane & 15;
    const int slice = blockIdx.x & (NSLICE - 1);
    const int p0    = (blockIdx.x >> 3) * BM;

    // direct-global A fragments for this wave's 32 rows:
    // afr[rt][kc] = X[p0 + wr*32 + rt*16 + mrow][kc*32 + quad*8 ..+7]
    short8 afr[2][4];
    #pragma unroll
    for (int rt = 0; rt < 2; ++rt)
        #pragma unroll
        for (int kc = 0; kc < 4; ++kc)
            afr[rt][kc] = *(const short8*)&Xb[(size_t)(p0 + wr * 32 + rt * 16 + mrow) * 128
                                              + kc * 32 + quad * 8];

    // wave 0: flags + has-flavor bits via ballot; ONE barrier total
    if (t < 64) {
        const int f = flagArr[p0 + t];
        sFlag[t] = f;
        const unsigned long long m0 = __ballot(f == 0);
        const unsigned long long m1 = __ballot(f == 1);
        if (t == 0) { sHas[0] = (m0 != 0ull); sHas[1] = (m1 != 0ull); }
    }
    __syncthreads();

    const int g0 = slice * 64 + wc * NTILE;   // first col-tile for this wave

    for (int phase = 0; phase < 2; ++phase) {
        if (!sHas[phase]) continue;          // flavor-pure blocks run one phase
        const uint4* __restrict__ yb = (phase ? Yf1q : Yf0q) + (size_t)g0 * 256 + lane;

        float rowsum[2][4] = {};             // unconditional per-phase exp-sums

        short8 b0 = *(const short8*)&yb[0];      // tile g0, kc0
        short8 b1 = *(const short8*)&yb[64];     // kc1
        short8 b2 = *(const short8*)&yb[128];    // kc2
        short8 b3 = *(const short8*)&yb[192];    // kc3

        #pragma unroll 1
        for (int jt = 0; jt < NTILE; ++jt) {
            float4v acc0 = {0.f, 0.f, 0.f, 0.f};
            float4v acc1 = {0.f, 0.f, 0.f, 0.f};
            acc0 = __builtin_amdgcn_mfma_f32_16x16x32_bf16(afr[0][0], b0, acc0, 0, 0, 0);
            acc1 = __builtin_amdgcn_mfma_f32_16x16x32_bf16(afr[1][0], b0, acc1, 0, 0, 0);
            acc0 = __builtin_amdgcn_mfma_f32_16x16x32_bf16(afr[0][1], b1, acc0, 0, 0, 0);
            acc1 = __builtin_amdgcn_mfma_f32_16x16x32_bf16(afr[1][1], b1, acc1, 0, 0, 0);
            if (jt < NTILE - 1) {                // prefetch next tile kc0/1 (~190cyc early)
                b0 = *(const short8*)&yb[256];
                b1 = *(const short8*)&yb[320];
            }
            acc0 = __builtin_amdgcn_mfma_f32_16x16x32_bf16(afr[0][2], b2, acc0, 0, 0, 0);
            acc1 = __builtin_amdgcn_mfma_f32_16x16x32_bf16(afr[1][2], b2, acc1, 0, 0, 0);
            acc0 = __builtin_amdgcn_mfma_f32_16x16x32_bf16(afr[0][3], b3, acc0, 0, 0, 0);
            acc1 = __builtin_amdgcn_mfma_f32_16x16x32_bf16(afr[1][3], b3, acc1, 0, 0, 0);
            if (jt < NTILE - 1) {                // prefetch next tile kc2/3
                b2 = *(const short8*)&yb[384];
                b3 = *(const short8*)&yb[448];
            }
            yb += 256;

            // fused exp-sum: exp((S-1)/T) == exp2(S*K1 + K2)  -> v_fma + v_exp + v_add
            #pragma unroll
            for (int r = 0; r < 4; ++r)
                rowsum[0][r] += exp2f(fmaf(acc0[r], K1, K2));
            #pragma unroll
            for (int r = 0; r < 4; ++r)
                rowsum[1][r] += exp2f(fmaf(acc1[r], K1, K2));
        }

        // reduce over the 16 col-lanes of each quad
        #pragma unroll
        for (int m = 1; m < 16; m <<= 1)
            #pragma unroll
            for (int rt = 0; rt < 2; ++rt)
                #pragma unroll
                for (int r = 0; r < 4; ++r)
                    rowsum[rt][r] += __shfl_xor(rowsum[rt][r], m);

        // flag-predicated packed atomic; 16th contributor writes the loss
        if (mrow == 0) {
            #pragma unroll
            for (int rt = 0; rt < 2; ++rt)
                #pragma unroll
                for (int r = 0; r < 4; ++r) {
                    const int row = wr * 32 + rt * 16 + quad * 4 + r;
                    if (sFlag[row] == phase) {
                        const unsigned long long add =
                            (unsigned long long)(rowsum[rt][r] * SCALE)
                            | (1ULL << CNT_SHIFT);
                        const unsigned long long ret =
                            atomicAdd(&lAcc64[p0 + row], add);
                        if ((ret >> CNT_SHIFT) == NCONTRIB - 1) {
                            const unsigned long long tot = (ret + add) & SUM_MASK;
                            const float s = (float)tot * INV_SCALE;
                            out[origArr[p0 + row]] =
                                logf(s) + INV_T - posArr[p0 + row] * INV_T;
                        }
                    }
                }
        }
    }
}

// ---------------- launch ----------------
extern "C" void kernel_launch(void* const* d_in, const int* in_sizes, int n_in,
                              void* d_out, int out_size, void* d_ws, size_t ws_size,
                              hipStream_t stream)
{
    const float4* fv = (const float4*)d_in[0];
    const float4* fi = (const float4*)d_in[1];
    const float4* v  = (const float4*)d_in[2];
    const float4* vi = (const float4*)d_in[3];
    float* out = (float*)d_out;

    unsigned short* Xb  = (unsigned short*)d_ws;   // [B,128] bf16 row-major, compacted X
    unsigned short* Yf0 = Xb  + Bsz * Dd;          // [B*128] bf16, B-fragment-ordered v
    unsigned short* Yf1 = Yf0 + Bsz * Dd;          // [B*128] bf16, B-fragment-ordered vi
    float* posArr = (float*)(Yf1 + Bsz * Dd);      // [B] positive logit (compacted idx)
    unsigned long long* lAcc64 =
        (unsigned long long*)(posArr + Bsz);       // [B] (count<<55 | sum*2^40)
    int*  origArr = (int*)(lAcc64 + Bsz);          // [B] compacted -> original row
    int*  flagArr = origArr + Bsz;                 // [B] flavor per compacted row
    unsigned long long* cnt = (unsigned long long*)(flagArr + Bsz);

    hipLaunchKernelGGL(init_kernel, dim3(1), dim3(64), 0, stream, cnt);
    hipLaunchKernelGGL(prep_kernel, dim3(Bsz / 32), dim3(1024), 0, stream,
                       fv, fi, v, vi, (unsigned*)Xb, (uint2*)Yf0, (uint2*)Yf1,
                       posArr, origArr, flagArr, lAcc64, cnt);
    hipLaunchKernelGGL(main_kernel, dim3((Bsz / BM) * NSLICE), dim3(256), 0, stream,
                       Xb, (const uint4*)Yf0, (const uint4*)Yf1, flagArr, lAcc64,
                       posArr, origArr, out);
}